// Round 7
// baseline (174.546 us; speedup 1.0000x reference)
//
#include <hip/hip_runtime.h>
#include <hip/hip_bf16.h>

#define LL 4096
#define DD 512
#define BB 8
#define KSEL 41

typedef __attribute__((ext_vector_type(4))) float f32x4;
typedef __attribute__((ext_vector_type(8))) short short8;

__device__ __forceinline__ ushort f2bf(float x) {
  __hip_bfloat16 h = __float2bfloat16(x);
  return *reinterpret_cast<ushort*>(&h);
}

__device__ __forceinline__ void g2lds16(const void* g, void* l) {
  __builtin_amdgcn_global_load_lds(
      (const __attribute__((address_space(1))) unsigned int*)g,
      (__attribute__((address_space(3))) unsigned int*)l, 16, 0, 0);
}

// ---- K1a: partial column sums (full-occupancy) ----
__global__ __launch_bounds__(512) void k_colsum(const float* __restrict__ q,
                                                const float* __restrict__ kk,
                                                float* __restrict__ qpart,
                                                float* __restrict__ kpart) {
  int lc = blockIdx.x, b = blockIdx.y, which = blockIdx.z;
  const float* src = which ? kk : q;
  float* part = which ? kpart : qpart;
  int c4 = (threadIdx.x & 127) * 4;
  int rg = threadIdx.x >> 7;  // 0..3 row-groups of 16
  float a0 = 0, a1 = 0, a2 = 0, a3 = 0;
  const float* p = src + ((size_t)b * LL + (size_t)lc * 64 + rg * 16) * DD + c4;
#pragma unroll
  for (int l = 0; l < 16; ++l) {
    float4 x = *(const float4*)(p + (size_t)l * DD);
    a0 += x.x; a1 += x.y; a2 += x.z; a3 += x.w;
  }
  float4 o = {a0, a1, a2, a3};
  *(float4*)&part[((size_t)b * 256 + lc * 4 + rg) * DD + c4] = o;
}

// ---- K1b: reduce 256 partials -> sq, sk [B][D] ----
__global__ __launch_bounds__(256) void k_colsum2(const float* __restrict__ qpart,
                                                 const float* __restrict__ kpart,
                                                 float* __restrict__ sq,
                                                 float* __restrict__ sk) {
  int b = blockIdx.x, which = blockIdx.y;
  int c = blockIdx.z * 256 + threadIdx.x;
  const float* part = which ? kpart : qpart;
  float* dst = which ? sk : sq;
  float acc = 0.f;
#pragma unroll 8
  for (int p = 0; p < 256; ++p) acc += part[((size_t)b * 256 + p) * DD + c];
  dst[(size_t)b * DD + c] = acc;
}

// ------- K2a: parallel partial projections: sq@Wq, sk@Wk, bv@Wo -------
__global__ __launch_bounds__(256) void k_proj(
    const float* __restrict__ sq, const float* __restrict__ sk,
    const float* __restrict__ Wq, const float* __restrict__ Wk,
    const float* __restrict__ bv, const float* __restrict__ Wo,
    float* __restrict__ partQ, float* __restrict__ partK,
    float* __restrict__ partO) {
  int jc = blockIdx.x;
  int which = blockIdx.y;
  int tid = threadIdx.x;
  int j0 = jc * 64;
  if (which == 2) {
    float a0 = 0.f, a1 = 0.f;
    for (int j = 0; j < 64; ++j) {
      float b = bv[j0 + j];
      a0 += b * Wo[(size_t)(j0 + j) * DD + tid];
      a1 += b * Wo[(size_t)(j0 + j) * DD + tid + 256];
    }
    partO[(size_t)jc * DD + tid] = a0;
    partO[(size_t)jc * DD + tid + 256] = a1;
    return;
  }
  const float* s = (which == 0) ? sq : sk;
  const float* W = (which == 0) ? Wq : Wk;
  __shared__ float ss[BB][64];
  for (int t = tid; t < BB * 64; t += 256)
    ss[t >> 6][t & 63] = s[(size_t)(t >> 6) * DD + j0 + (t & 63)];
  __syncthreads();
  float a[BB][2];
#pragma unroll
  for (int b = 0; b < BB; ++b) { a[b][0] = 0.f; a[b][1] = 0.f; }
  for (int j = 0; j < 64; ++j) {
    float w0 = W[(size_t)(j0 + j) * DD + tid];
    float w1 = W[(size_t)(j0 + j) * DD + tid + 256];
#pragma unroll
    for (int b = 0; b < BB; ++b) {
      float sv = ss[b][j];
      a[b][0] += sv * w0;
      a[b][1] += sv * w1;
    }
  }
  float* part = (which == 0) ? partQ : partK;
#pragma unroll
  for (int b = 0; b < BB; ++b) {
    part[((size_t)jc * BB + b) * DD + tid] = a[b][0];
    part[((size_t)jc * BB + b) * DD + tid + 256] = a[b][1];
  }
}

// ------- K2b: reduce partials, mean_value, top-41, softmax, bvo -------
__global__ __launch_bounds__(512) void k_stats2(
    const float* __restrict__ partQ, const float* __restrict__ partK,
    const float* __restrict__ partO,
    const float* __restrict__ bq, const float* __restrict__ bk,
    const float* __restrict__ bo,
    int* __restrict__ idx_out, float* __restrict__ wts_out,
    float* __restrict__ bvo_out) {
  __shared__ float Sq[BB][DD];
  __shared__ float Sk[BB][DD];
  __shared__ float mvs[BB][64];
  __shared__ float mab[64];
  __shared__ int idxs[64];
  int tid = threadIdx.x;
  float bqv = bq[tid] * (float)LL, bkv = bk[tid] * (float)LL;
#pragma unroll
  for (int b = 0; b < BB; ++b) {
    float aq = 0.f, ak = 0.f;
#pragma unroll
    for (int jc = 0; jc < 8; ++jc) {
      aq += partQ[((size_t)jc * BB + b) * DD + tid];
      ak += partK[((size_t)jc * BB + b) * DD + tid];
    }
    Sq[b][tid] = aq + bqv;
    Sk[b][tid] = ak + bkv;
  }
  {
    float ao = 0.f;
#pragma unroll
    for (int jc = 0; jc < 8; ++jc) ao += partO[(size_t)jc * DD + tid];
    bvo_out[tid] = ao + bo[tid];
  }
  __syncthreads();
  {
    int b = tid >> 6, d = tid & 63;
    float s = 0.f;
#pragma unroll
    for (int h = 0; h < 8; ++h) s += Sq[b][h * 64 + d] * Sk[b][h * 64 + d];
    mvs[b][d] = s * (1.0f / ((float)LL * 8.0f));
  }
  __syncthreads();
  if (tid < 64) {
    float s = 0.f;
#pragma unroll
    for (int b = 0; b < BB; ++b) s += mvs[b][tid];
    mab[tid] = s * 0.125f;
  }
  __syncthreads();
  if (tid < 64) {
    float x = mab[tid];
    int r = 0;
    for (int d = 0; d < 64; ++d) {
      float y = mab[d];
      r += (y > x || (y == x && d < tid)) ? 1 : 0;
    }
    if (r < KSEL) { idxs[r] = tid; idx_out[r] = tid; }
  }
  __syncthreads();
  if (tid < BB) {
    int b = tid;
    float mx = -3.4e38f;
    for (int i = 0; i < KSEL; ++i) mx = fmaxf(mx, mvs[b][idxs[i]]);
    float s = 0.f;
    for (int i = 0; i < KSEL; ++i) s += expf(mvs[b][idxs[i]] - mx);
    float inv = 1.f / s;
    for (int i = 0; i < KSEL; ++i) wts_out[b * 64 + i] = expf(mvs[b][idxs[i]] - mx) * inv;
  }
}

// ------- K3: Wvo^T (bf16) = (Wv @ Wo)^T, fused -------
__global__ __launch_bounds__(256) void k_wvot(const float* __restrict__ Wv,
                                              const float* __restrict__ Wo,
                                              ushort* __restrict__ WT) {
  __shared__ float wv[8][512];
  int tid = threadIdx.x;
  int c = blockIdx.x * 256 + tid;
  int j0 = blockIdx.y * 8;
  for (int t = tid; t < 8 * 512; t += 256)
    wv[t >> 9][t & 511] = Wv[(size_t)(j0 + (t >> 9)) * DD + (t & 511)];
  __syncthreads();
  float acc[8] = {0, 0, 0, 0, 0, 0, 0, 0};
  for (int m = 0; m < DD; ++m) {
    float wo = Wo[(size_t)m * DD + c];
#pragma unroll
    for (int j = 0; j < 8; ++j) acc[j] += wv[j][m] * wo;
  }
  ushort4 o0, o1;
  o0.x = f2bf(acc[0]); o0.y = f2bf(acc[1]); o0.z = f2bf(acc[2]); o0.w = f2bf(acc[3]);
  o1.x = f2bf(acc[4]); o1.y = f2bf(acc[5]); o1.z = f2bf(acc[6]); o1.w = f2bf(acc[7]);
  *(ushort4*)&WT[(size_t)c * DD + j0] = o0;
  *(ushort4*)&WT[(size_t)c * DD + j0 + 4] = o1;
}

// -------- K4: fused conv+gemm --------
// Per block: one 64-row l-tile of one batch.
//  P1: stage v-window [128 rows][512 ch] -> vwinT[c][j] bf16; build band M.
//  P2: conv MFMA -> 64x512 tile (regs) -> vagg LDS [64][520] bf16.
//  P3: gemm: out(64x512,f32) = vagg @ Wvo + bvo, WvoT staged per-64-k panel
//      with the k_gemm XOR-swizzle.
struct SmP1 {
  ushort vwinT[512 * 136];  // 139264 B
  ushort M[64 * 136];       // 17408 B
  float coefw[256];         // 1024 B
};
struct SmP2 {
  ushort vagg[64 * 520];    // 66560 B
  ushort lB[512 * 64];      // 65536 B
};
union SmemU { SmP1 p1; SmP2 p2; };

__global__ __launch_bounds__(512, 1) void k_convgemm(
    const float* __restrict__ v, const int* __restrict__ idx,
    const float* __restrict__ wts, const ushort* __restrict__ WvoT,
    const float* __restrict__ bvo, float* __restrict__ C) {
  __shared__ SmemU sm;
  int lt = blockIdx.x;  // 64 l-tiles
  int b = blockIdx.y;   // 8 batches
  int tid = threadIdx.x;
  int l0 = lt * 64;
  int lane = tid & 63, w = tid >> 6;
  int r15 = lane & 15, g = lane >> 4;

  // --- coef table ---
  if (tid < 256) sm.p1.coefw[tid] = 0.f;
  __syncthreads();
  if (tid < KSEL) sm.p1.coefw[64 + idx[tid]] = wts[b * 64 + tid];

  // --- stage v window: vwinT[c][j] = bf16(v[b][(l0+j)&4095][c]) ---
  {
    int c = tid;  // 512 threads = 512 channels
    const float* vb = v + (size_t)b * LL * DD + c;
#pragma unroll
    for (int it = 0; it < 16; ++it) {
      int j0 = it * 8;
      union { unsigned int u[4]; short8 s; } pk;
#pragma unroll
      for (int p = 0; p < 4; ++p) {
        int ja = (l0 + j0 + 2 * p) & (LL - 1);
        int jb = (l0 + j0 + 2 * p + 1) & (LL - 1);
        float lo = vb[(size_t)ja * DD];
        float hi = vb[(size_t)jb * DD];
        pk.u[p] = (unsigned)f2bf(lo) | ((unsigned)f2bf(hi) << 16);
      }
      *(short8*)&sm.p1.vwinT[c * 136 + j0] = pk.s;
    }
  }
  __syncthreads();  // coefw ready (M build reads it)
  // --- build M[r][j] = bf16(coefw[64 + j - r]) ---
#pragma unroll
  for (int it = 0; it < 4; ++it) {
    int e = it * 512 + tid;   // 2048 quads = 64 rows x 32 quads
    int r = e >> 5, j0 = (e & 31) * 4;
    ushort4 m4;
    m4.x = f2bf(sm.p1.coefw[64 + j0 + 0 - r]);
    m4.y = f2bf(sm.p1.coefw[64 + j0 + 1 - r]);
    m4.z = f2bf(sm.p1.coefw[64 + j0 + 2 - r]);
    m4.w = f2bf(sm.p1.coefw[64 + j0 + 3 - r]);
    *(ushort4*)&sm.p1.M[r * 136 + j0] = m4;
  }
  __syncthreads();

  // --- conv MFMA: wave w owns ch chunk [w*64, w*64+64) ---
  f32x4 acc[4][4] = {};
#pragma unroll
  for (int ks = 0; ks < 4; ++ks) {
    int kc = ks * 4 + g;
    short8 av[4], bvv[4];
#pragma unroll
    for (int m = 0; m < 4; ++m)
      av[m] = *(const short8*)&sm.p1.M[(m * 16 + r15) * 136 + kc * 8];
#pragma unroll
    for (int n = 0; n < 4; ++n)
      bvv[n] = *(const short8*)&sm.p1.vwinT[(w * 64 + n * 16 + r15) * 136 + kc * 8];
#pragma unroll
    for (int m = 0; m < 4; ++m)
#pragma unroll
      for (int n = 0; n < 4; ++n)
        acc[m][n] = __builtin_amdgcn_mfma_f32_16x16x32_bf16(av[m], bvv[n], acc[m][n], 0, 0, 0);
  }
  __syncthreads();  // all vwinT/M reads done before overlay write

  // --- dump conv tile to LDS vagg[64][520] bf16 ---
#pragma unroll
  for (int m = 0; m < 4; ++m)
#pragma unroll
    for (int n = 0; n < 4; ++n)
#pragma unroll
      for (int r = 0; r < 4; ++r) {
        int row = m * 16 + g * 4 + r;
        int cc = w * 64 + n * 16 + r15;
        sm.p2.vagg[row * 520 + cc] = f2bf(acc[m][n][r]);
      }
  __syncthreads();

  // --- gemm: out = vagg(64x512) @ Wvo(512x512) ---
  f32x4 acc2[4][4] = {};
  for (int k0 = 0; k0 < DD; k0 += 64) {
#pragma unroll
    for (int it = 0; it < 8; ++it) {
      int e = it * 512 + tid;   // 4096 chunk-slots = 512 rows x 8 chunks
      int o = e >> 3;
      int clg = (e & 7) ^ (o & 7);
      g2lds16(WvoT + (size_t)o * DD + k0 + clg * 8, &sm.p2.lB[e * 8]);
    }
    asm volatile("s_waitcnt vmcnt(0)" ::: "memory");
    __syncthreads();
#pragma unroll
    for (int ks = 0; ks < 2; ++ks) {
      int kc = ks * 4 + g;
      int kk = k0 + kc * 8;
      short8 av[4], bvv[4];
#pragma unroll
      for (int m = 0; m < 4; ++m)
        av[m] = *(const short8*)&sm.p2.vagg[(m * 16 + r15) * 520 + kk];
#pragma unroll
      for (int n = 0; n < 4; ++n) {
        int col = w * 64 + n * 16 + r15;
        bvv[n] = *(const short8*)&sm.p2.lB[(col * 8 + (kc ^ (col & 7))) * 8];
      }
#pragma unroll
      for (int m = 0; m < 4; ++m)
#pragma unroll
        for (int n = 0; n < 4; ++n)
          acc2[m][n] = __builtin_amdgcn_mfma_f32_16x16x32_bf16(av[m], bvv[n], acc2[m][n], 0, 0, 0);
    }
    __syncthreads();
  }

  // --- epilogue: out += bvo ---
  float* Cb = C + ((size_t)b * LL + l0) * DD;
#pragma unroll
  for (int n = 0; n < 4; ++n) {
    int col = w * 64 + n * 16 + r15;
    float bc = bvo[col];
#pragma unroll
    for (int m = 0; m < 4; ++m) {
      int row = m * 16 + g * 4;
#pragma unroll
      for (int r = 0; r < 4; ++r)
        Cb[(size_t)(row + r) * DD + col] = acc2[m][n][r] + bc;
    }
  }
}

extern "C" void kernel_launch(void* const* d_in, const int* in_sizes, int n_in,
                              void* d_out, int out_size, void* d_ws, size_t ws_size,
                              hipStream_t stream) {
  const float* q  = (const float*)d_in[0];
  const float* k  = (const float*)d_in[1];
  const float* v  = (const float*)d_in[2];
  const float* Wq = (const float*)d_in[3];
  const float* bq = (const float*)d_in[4];
  const float* Wk = (const float*)d_in[5];
  const float* bk = (const float*)d_in[6];
  const float* Wv = (const float*)d_in[7];
  const float* bv = (const float*)d_in[8];
  const float* Wo = (const float*)d_in[9];
  const float* bo = (const float*)d_in[10];
  float* out = (float*)d_out;

  char* ws = (char*)d_ws;
  ushort* wvot  = (ushort*)(ws + 0x2100000);  // 512 KB bf16 [D][D] transposed
  float* sq     = (float*)(ws + 0x2380000);   // 16 KB
  float* sk     = (float*)(ws + 0x2384000);   // 16 KB
  int*   idx    = (int*)(ws + 0x2388800);     // 256 B
  float* wts    = (float*)(ws + 0x2388900);   // 2 KB
  float* bvo    = (float*)(ws + 0x2389100);   // 2 KB
  float* qpart  = (float*)(ws + 0x0);         // 4 MB [8][256][512]
  float* kpart  = (float*)(ws + 0x400000);    // 4 MB
  float* partQ  = (float*)(ws + 0x2180000);   // 128 KB
  float* partK  = (float*)(ws + 0x21A0000);   // 128 KB
  float* partO  = (float*)(ws + 0x21C0000);   // 16 KB

  k_colsum<<<dim3(64, 8, 2), 512, 0, stream>>>(q, k, qpart, kpart);
  k_colsum2<<<dim3(8, 2, 2), 256, 0, stream>>>(qpart, kpart, sq, sk);
  k_proj<<<dim3(8, 3), 256, 0, stream>>>(sq, sk, Wq, Wk, bv, Wo, partQ, partK, partO);
  k_stats2<<<dim3(1), 512, 0, stream>>>(partQ, partK, partO, bq, bk, bo, idx, wts, bvo);
  k_wvot<<<dim3(2, 64), 256, 0, stream>>>(Wv, Wo, wvot);
  k_convgemm<<<dim3(64, 8), 512, 0, stream>>>(v, idx, wts, wvot, bvo, out);
}

// Round 9
// 145.980 us; speedup vs baseline: 1.1957x; 1.1957x over previous
//
#include <hip/hip_runtime.h>
#include <hip/hip_bf16.h>

#define LL 4096
#define DD 512
#define BB 8
#define KSEL 41

typedef __attribute__((ext_vector_type(4))) float f32x4;
typedef __attribute__((ext_vector_type(8))) short short8;

__device__ __forceinline__ ushort f2bf(float x) {
  __hip_bfloat16 h = __float2bfloat16(x);
  return *reinterpret_cast<ushort*>(&h);
}

__device__ __forceinline__ void g2lds16(const void* g, void* l) {
  __builtin_amdgcn_global_load_lds(
      (const __attribute__((address_space(1))) unsigned int*)g,
      (__attribute__((address_space(3))) unsigned int*)l, 16, 0, 0);
}

// ---- K1a: column sums, wave-sequential streaming + nontemporal loads ----
// grid (16 chunks of 256 rows, 8 b, 2 which), 512 thr = 8 waves.
// Wave w streams rows [lc*256+w*32, +32) fully sequentially (2KB/row, 32B/lane).
__global__ __launch_bounds__(512) void k_colsum(const float* __restrict__ q,
                                                const float* __restrict__ kk,
                                                float* __restrict__ qpart,
                                                float* __restrict__ kpart) {
  int lc = blockIdx.x, b = blockIdx.y, which = blockIdx.z;
  const float* src = which ? kk : q;
  float* part = which ? kpart : qpart;
  int lane = threadIdx.x & 63, w = threadIdx.x >> 6;
  int c8 = lane * 8;
  const float* p = src + ((size_t)b * LL + (size_t)lc * 256 + w * 32) * DD + c8;
  float a0 = 0, a1 = 0, a2 = 0, a3 = 0, a4 = 0, a5 = 0, a6 = 0, a7 = 0;
#pragma unroll 4
  for (int l = 0; l < 32; ++l) {
    f32x4 x = __builtin_nontemporal_load((const f32x4*)(p + (size_t)l * DD));
    f32x4 y = __builtin_nontemporal_load((const f32x4*)(p + (size_t)l * DD + 4));
    a0 += x[0]; a1 += x[1]; a2 += x[2]; a3 += x[3];
    a4 += y[0]; a5 += y[1]; a6 += y[2]; a7 += y[3];
  }
  float* dst = &part[((size_t)b * 128 + lc * 8 + w) * DD + c8];
  f32x4 o0 = {a0, a1, a2, a3}, o1 = {a4, a5, a6, a7};
  *(f32x4*)dst = o0;
  *(f32x4*)(dst + 4) = o1;
}

// ---- K1b: reduce 128 partials -> sq, sk [B][D] ----
__global__ __launch_bounds__(256) void k_colsum2(const float* __restrict__ qpart,
                                                 const float* __restrict__ kpart,
                                                 float* __restrict__ sq,
                                                 float* __restrict__ sk) {
  int b = blockIdx.x, which = blockIdx.y;
  int c = blockIdx.z * 256 + threadIdx.x;
  const float* part = which ? kpart : qpart;
  float* dst = which ? sk : sq;
  float acc = 0.f;
#pragma unroll 8
  for (int p = 0; p < 128; ++p) acc += part[((size_t)b * 128 + p) * DD + c];
  dst[(size_t)b * DD + c] = acc;
}

// ------- K2a: parallel partial projections: sq@Wq, sk@Wk, bv@Wo -------
__global__ __launch_bounds__(256) void k_proj(
    const float* __restrict__ sq, const float* __restrict__ sk,
    const float* __restrict__ Wq, const float* __restrict__ Wk,
    const float* __restrict__ bv, const float* __restrict__ Wo,
    float* __restrict__ partQ, float* __restrict__ partK,
    float* __restrict__ partO) {
  int jc = blockIdx.x;
  int which = blockIdx.y;
  int tid = threadIdx.x;
  int j0 = jc * 64;
  if (which == 2) {
    float a0 = 0.f, a1 = 0.f;
    for (int j = 0; j < 64; ++j) {
      float b = bv[j0 + j];
      a0 += b * Wo[(size_t)(j0 + j) * DD + tid];
      a1 += b * Wo[(size_t)(j0 + j) * DD + tid + 256];
    }
    partO[(size_t)jc * DD + tid] = a0;
    partO[(size_t)jc * DD + tid + 256] = a1;
    return;
  }
  const float* s = (which == 0) ? sq : sk;
  const float* W = (which == 0) ? Wq : Wk;
  __shared__ float ss[BB][64];
  for (int t = tid; t < BB * 64; t += 256)
    ss[t >> 6][t & 63] = s[(size_t)(t >> 6) * DD + j0 + (t & 63)];
  __syncthreads();
  float a[BB][2];
#pragma unroll
  for (int b = 0; b < BB; ++b) { a[b][0] = 0.f; a[b][1] = 0.f; }
  for (int j = 0; j < 64; ++j) {
    float w0 = W[(size_t)(j0 + j) * DD + tid];
    float w1 = W[(size_t)(j0 + j) * DD + tid + 256];
#pragma unroll
    for (int b = 0; b < BB; ++b) {
      float sv = ss[b][j];
      a[b][0] += sv * w0;
      a[b][1] += sv * w1;
    }
  }
  float* part = (which == 0) ? partQ : partK;
#pragma unroll
  for (int b = 0; b < BB; ++b) {
    part[((size_t)jc * BB + b) * DD + tid] = a[b][0];
    part[((size_t)jc * BB + b) * DD + tid + 256] = a[b][1];
  }
}

// ------- K2b: reduce partials, mean_value, top-41, softmax, bvo -------
__global__ __launch_bounds__(512) void k_stats2(
    const float* __restrict__ partQ, const float* __restrict__ partK,
    const float* __restrict__ partO,
    const float* __restrict__ bq, const float* __restrict__ bk,
    const float* __restrict__ bo,
    int* __restrict__ idx_out, float* __restrict__ wts_out,
    float* __restrict__ bvo_out) {
  __shared__ float Sq[BB][DD];
  __shared__ float Sk[BB][DD];
  __shared__ float mvs[BB][64];
  __shared__ float mab[64];
  __shared__ int idxs[64];
  int tid = threadIdx.x;
  float bqv = bq[tid] * (float)LL, bkv = bk[tid] * (float)LL;
#pragma unroll
  for (int b = 0; b < BB; ++b) {
    float aq = 0.f, ak = 0.f;
#pragma unroll
    for (int jc = 0; jc < 8; ++jc) {
      aq += partQ[((size_t)jc * BB + b) * DD + tid];
      ak += partK[((size_t)jc * BB + b) * DD + tid];
    }
    Sq[b][tid] = aq + bqv;
    Sk[b][tid] = ak + bkv;
  }
  {
    float ao = 0.f;
#pragma unroll
    for (int jc = 0; jc < 8; ++jc) ao += partO[(size_t)jc * DD + tid];
    bvo_out[tid] = ao + bo[tid];
  }
  __syncthreads();
  {
    int b = tid >> 6, d = tid & 63;
    float s = 0.f;
#pragma unroll
    for (int h = 0; h < 8; ++h) s += Sq[b][h * 64 + d] * Sk[b][h * 64 + d];
    mvs[b][d] = s * (1.0f / ((float)LL * 8.0f));
  }
  __syncthreads();
  if (tid < 64) {
    float s = 0.f;
#pragma unroll
    for (int b = 0; b < BB; ++b) s += mvs[b][tid];
    mab[tid] = s * 0.125f;
  }
  __syncthreads();
  if (tid < 64) {
    float x = mab[tid];
    int r = 0;
    for (int d = 0; d < 64; ++d) {
      float y = mab[d];
      r += (y > x || (y == x && d < tid)) ? 1 : 0;
    }
    if (r < KSEL) { idxs[r] = tid; idx_out[r] = tid; }
  }
  __syncthreads();
  if (tid < BB) {
    int b = tid;
    float mx = -3.4e38f;
    for (int i = 0; i < KSEL; ++i) mx = fmaxf(mx, mvs[b][idxs[i]]);
    float s = 0.f;
    for (int i = 0; i < KSEL; ++i) s += expf(mvs[b][idxs[i]] - mx);
    float inv = 1.f / s;
    for (int i = 0; i < KSEL; ++i) wts_out[b * 64 + i] = expf(mvs[b][idxs[i]] - mx) * inv;
  }
}

// ------- K3: Wvo^T (bf16) = (Wv @ Wo)^T, fused -------
__global__ __launch_bounds__(256) void k_wvot(const float* __restrict__ Wv,
                                              const float* __restrict__ Wo,
                                              ushort* __restrict__ WT) {
  __shared__ float wv[8][512];
  int tid = threadIdx.x;
  int c = blockIdx.x * 256 + tid;
  int j0 = blockIdx.y * 8;
  for (int t = tid; t < 8 * 512; t += 256)
    wv[t >> 9][t & 511] = Wv[(size_t)(j0 + (t >> 9)) * DD + (t & 511)];
  __syncthreads();
  float acc[8] = {0, 0, 0, 0, 0, 0, 0, 0};
  for (int m = 0; m < DD; ++m) {
    float wo = Wo[(size_t)m * DD + c];
#pragma unroll
    for (int j = 0; j < 8; ++j) acc[j] += wv[j][m] * wo;
  }
  ushort4 o0, o1;
  o0.x = f2bf(acc[0]); o0.y = f2bf(acc[1]); o0.z = f2bf(acc[2]); o0.w = f2bf(acc[3]);
  o1.x = f2bf(acc[4]); o1.y = f2bf(acc[5]); o1.z = f2bf(acc[6]); o1.w = f2bf(acc[7]);
  *(ushort4*)&WT[(size_t)c * DD + j0] = o0;
  *(ushort4*)&WT[(size_t)c * DD + j0 + 4] = o1;
}

// -------- K4: vagg = conv(v) via MFMA (split version) --------
__global__ __launch_bounds__(256) void k_conv(const float* __restrict__ v,
                                              const int* __restrict__ idx,
                                              const float* __restrict__ wts,
                                              ushort* __restrict__ vagg) {
  __shared__ ushort vwinT[128 * 136];
  __shared__ ushort Mlds[64 * 136];
  __shared__ float coefw[256];
  int lt = blockIdx.x;
  int ch0 = blockIdx.y * 128;
  int b = blockIdx.z;
  int tid = threadIdx.x;
  int l0 = lt * 64;

  coefw[tid] = 0.f;
  __syncthreads();
  if (tid < KSEL) coefw[64 + idx[tid]] = wts[b * 64 + tid];
  __syncthreads();

  {
    int c = tid & 127;
    int jh = tid >> 7;
    const float* vb = v + (size_t)b * LL * DD + ch0 + c;
#pragma unroll
    for (int it = 0; it < 8; ++it) {
      int j0 = (it * 2 + jh) * 8;
      union { unsigned int u[4]; short8 s; } pk;
#pragma unroll
      for (int p = 0; p < 4; ++p) {
        int ja = (l0 + j0 + 2 * p) & (LL - 1);
        int jb = (l0 + j0 + 2 * p + 1) & (LL - 1);
        float lo = vb[(size_t)ja * DD];
        float hi = vb[(size_t)jb * DD];
        pk.u[p] = (unsigned)f2bf(lo) | ((unsigned)f2bf(hi) << 16);
      }
      *(short8*)&vwinT[c * 136 + j0] = pk.s;
    }
  }
#pragma unroll
  for (int it = 0; it < 8; ++it) {
    int e = (it * 256 + tid) * 4;
    int r = e >> 7, j0 = e & 127;
    ushort4 m4;
    m4.x = f2bf(coefw[64 + j0 + 0 - r]);
    m4.y = f2bf(coefw[64 + j0 + 1 - r]);
    m4.z = f2bf(coefw[64 + j0 + 2 - r]);
    m4.w = f2bf(coefw[64 + j0 + 3 - r]);
    *(ushort4*)&Mlds[r * 136 + j0] = m4;
  }
  __syncthreads();

  int lane = tid & 63, w = tid >> 6;
  int r15 = lane & 15, g = lane >> 4;
  f32x4 acc[4][2] = {};
#pragma unroll
  for (int ks = 0; ks < 4; ++ks) {
    int kc = ks * 4 + g;
    short8 av[4], bvv[2];
#pragma unroll
    for (int m = 0; m < 4; ++m)
      av[m] = *(const short8*)&Mlds[(m * 16 + r15) * 136 + kc * 8];
#pragma unroll
    for (int n = 0; n < 2; ++n)
      bvv[n] = *(const short8*)&vwinT[(w * 32 + n * 16 + r15) * 136 + kc * 8];
#pragma unroll
    for (int m = 0; m < 4; ++m)
#pragma unroll
      for (int n = 0; n < 2; ++n)
        acc[m][n] = __builtin_amdgcn_mfma_f32_16x16x32_bf16(av[m], bvv[n], acc[m][n], 0, 0, 0);
  }

  ushort* vout = vagg + ((size_t)b * LL + l0) * DD + ch0;
#pragma unroll
  for (int m = 0; m < 4; ++m)
#pragma unroll
    for (int n = 0; n < 2; ++n)
#pragma unroll
      for (int r = 0; r < 4; ++r) {
        int row = m * 16 + g * 4 + r;
        int col = w * 32 + n * 16 + r15;
        vout[(size_t)row * DD + col] = f2bf(acc[m][n][r]);
      }
}

// -------- K5: out = vagg(bf16) @ Wvo(bf16, stored transposed) + bvo  (f32) --------
__global__ __launch_bounds__(256) void k_gemm(const ushort* __restrict__ A,
                                              const ushort* __restrict__ BT,
                                              const float* __restrict__ bias,
                                              float* __restrict__ C) {
  __shared__ ushort lA[128 * 64];
  __shared__ ushort lB[128 * 64];
  int bcol = blockIdx.x * 128;
  int brow = blockIdx.y * 128;
  int tid = threadIdx.x;
  int lane = tid & 63, wid = tid >> 6;
  int wr = wid >> 1, wc = wid & 1;
  int r15 = lane & 15, g = lane >> 4;
  f32x4 acc[4][4] = {};
  for (int k0 = 0; k0 < DD; k0 += 64) {
#pragma unroll
    for (int it = 0; it < 4; ++it) {
      int ch = it * 256 + tid;
      int row = ch >> 3;
      int clg = (ch & 7) ^ (row & 7);
      g2lds16(A + (size_t)(brow + row) * DD + k0 + clg * 8, &lA[ch * 8]);
      g2lds16(BT + (size_t)(bcol + row) * DD + k0 + clg * 8, &lB[ch * 8]);
    }
    asm volatile("s_waitcnt vmcnt(0)" ::: "memory");
    __syncthreads();
#pragma unroll
    for (int ks = 0; ks < 2; ++ks) {
      int kc = ks * 4 + g;
      short8 av[4], bv[4];
#pragma unroll
      for (int m = 0; m < 4; ++m) {
        int row = wr * 64 + m * 16 + r15;
        av[m] = *(const short8*)&lA[(row * 8 + (kc ^ (row & 7))) * 8];
        int col = wc * 64 + m * 16 + r15;
        bv[m] = *(const short8*)&lB[(col * 8 + (kc ^ (col & 7))) * 8];
      }
#pragma unroll
      for (int m = 0; m < 4; ++m)
#pragma unroll
        for (int n = 0; n < 4; ++n)
          acc[m][n] = __builtin_amdgcn_mfma_f32_16x16x32_bf16(av[m], bv[n], acc[m][n], 0, 0, 0);
    }
    __syncthreads();
  }
#pragma unroll
  for (int n = 0; n < 4; ++n) {
    int col = bcol + wc * 64 + n * 16 + r15;
    float bc = bias[col];
#pragma unroll
    for (int m = 0; m < 4; ++m) {
      int row = brow + wr * 64 + m * 16 + g * 4;
#pragma unroll
      for (int r = 0; r < 4; ++r)
        C[(size_t)(row + r) * DD + col] = acc[m][n][r] + bc;
    }
  }
}

extern "C" void kernel_launch(void* const* d_in, const int* in_sizes, int n_in,
                              void* d_out, int out_size, void* d_ws, size_t ws_size,
                              hipStream_t stream) {
  const float* q  = (const float*)d_in[0];
  const float* k  = (const float*)d_in[1];
  const float* v  = (const float*)d_in[2];
  const float* Wq = (const float*)d_in[3];
  const float* bq = (const float*)d_in[4];
  const float* Wk = (const float*)d_in[5];
  const float* bk = (const float*)d_in[6];
  const float* Wv = (const float*)d_in[7];
  const float* bv = (const float*)d_in[8];
  const float* Wo = (const float*)d_in[9];
  const float* bo = (const float*)d_in[10];
  float* out = (float*)d_out;

  char* ws = (char*)d_ws;
  ushort* vagg  = (ushort*)(ws + 0x0);        // 32 MB bf16 [B*L*D]
  ushort* wvot  = (ushort*)(ws + 0x2100000);  // 512 KB bf16 [D][D] transposed
  float* sq     = (float*)(ws + 0x2380000);   // 16 KB
  float* sk     = (float*)(ws + 0x2384000);   // 16 KB
  int*   idx    = (int*)(ws + 0x2388800);     // 256 B
  float* wts    = (float*)(ws + 0x2388900);   // 2 KB
  float* bvo    = (float*)(ws + 0x2389100);   // 2 KB
  // colsum partials overlay vagg region (dead until k_conv, stream-ordered):
  float* qpart  = (float*)(ws + 0x0);         // 2 MB [8][128][512]
  float* kpart  = (float*)(ws + 0x200000);    // 2 MB
  // proj partials (dead after k_stats2):
  float* partQ  = (float*)(ws + 0x2180000);   // 128 KB
  float* partK  = (float*)(ws + 0x21A0000);   // 128 KB
  float* partO  = (float*)(ws + 0x21C0000);   // 16 KB

  k_colsum<<<dim3(16, 8, 2), 512, 0, stream>>>(q, k, qpart, kpart);
  k_colsum2<<<dim3(8, 2, 2), 256, 0, stream>>>(qpart, kpart, sq, sk);
  k_proj<<<dim3(8, 3), 256, 0, stream>>>(sq, sk, Wq, Wk, bv, Wo, partQ, partK, partO);
  k_stats2<<<dim3(1), 512, 0, stream>>>(partQ, partK, partO, bq, bk, bo, idx, wts, bvo);
  k_wvot<<<dim3(2, 64), 256, 0, stream>>>(Wv, Wo, wvot);
  k_conv<<<dim3(64, 4, 8), 256, 0, stream>>>(v, idx, wts, vagg);
  k_gemm<<<dim3(4, 256), 256, 0, stream>>>(vagg, wvot, bvo, out);
}

// Round 10
// 128.872 us; speedup vs baseline: 1.3544x; 1.1328x over previous
//
#include <hip/hip_runtime.h>
#include <hip/hip_bf16.h>

#define LL 4096
#define DD 512
#define BB 8
#define KSEL 41

typedef __attribute__((ext_vector_type(4))) float f32x4;
typedef __attribute__((ext_vector_type(8))) short short8;

__device__ __forceinline__ ushort f2bf(float x) {
  __hip_bfloat16 h = __float2bfloat16(x);
  return *reinterpret_cast<ushort*>(&h);
}

__device__ __forceinline__ void g2lds16(const void* g, void* l) {
  __builtin_amdgcn_global_load_lds(
      (const __attribute__((address_space(1))) unsigned int*)g,
      (__attribute__((address_space(3))) unsigned int*)l, 16, 0, 0);
}

// ---- K1: column sums, wave-sequential streaming + nontemporal loads ----
__global__ __launch_bounds__(512) void k_colsum(const float* __restrict__ q,
                                                const float* __restrict__ kk,
                                                float* __restrict__ qpart,
                                                float* __restrict__ kpart) {
  int lc = blockIdx.x, b = blockIdx.y, which = blockIdx.z;
  const float* src = which ? kk : q;
  float* part = which ? kpart : qpart;
  int lane = threadIdx.x & 63, w = threadIdx.x >> 6;
  int c8 = lane * 8;
  const float* p = src + ((size_t)b * LL + (size_t)lc * 256 + w * 32) * DD + c8;
  float a0 = 0, a1 = 0, a2 = 0, a3 = 0, a4 = 0, a5 = 0, a6 = 0, a7 = 0;
#pragma unroll 8
  for (int l = 0; l < 32; ++l) {
    f32x4 x = __builtin_nontemporal_load((const f32x4*)(p + (size_t)l * DD));
    f32x4 y = __builtin_nontemporal_load((const f32x4*)(p + (size_t)l * DD + 4));
    a0 += x[0]; a1 += x[1]; a2 += x[2]; a3 += x[3];
    a4 += y[0]; a5 += y[1]; a6 += y[2]; a7 += y[3];
  }
  float* dst = &part[((size_t)b * 128 + lc * 8 + w) * DD + c8];
  f32x4 o0 = {a0, a1, a2, a3}, o1 = {a4, a5, a6, a7};
  *(f32x4*)dst = o0;
  *(f32x4*)(dst + 4) = o1;
}

// ---- K2: merged {partial projections (reduce partials inline)} + {WvoT} ----
// blocks 0..23: proj (jc = bid&7, which = bid>>3); blocks 24..151: wvot.
__global__ __launch_bounds__(256) void k_projw(
    const float* __restrict__ qpart, const float* __restrict__ kpart,
    const float* __restrict__ Wq, const float* __restrict__ Wk,
    const float* __restrict__ bv, const float* __restrict__ Wo,
    const float* __restrict__ Wv,
    float* __restrict__ partQ, float* __restrict__ partK,
    float* __restrict__ partO, ushort* __restrict__ WT) {
  __shared__ float ss[BB][64];     // proj path (2 KB)
  __shared__ float wv[8][512];     // wvot path (16 KB)
  int bid = blockIdx.x;
  int tid = threadIdx.x;

  if (bid < 24) {
    int jc = bid & 7, which = bid >> 3;
    int j0 = jc * 64;
    if (which == 2) {
      float a0 = 0.f, a1 = 0.f;
      for (int j = 0; j < 64; ++j) {
        float b = bv[j0 + j];
        a0 += b * Wo[(size_t)(j0 + j) * DD + tid];
        a1 += b * Wo[(size_t)(j0 + j) * DD + tid + 256];
      }
      partO[(size_t)jc * DD + tid] = a0;
      partO[(size_t)jc * DD + tid + 256] = a1;
      return;
    }
    const float* part_in = which ? kpart : qpart;
    const float* W = which ? Wk : Wq;
    // reduce 128 colsum partials for this j-slice directly (replaces k_colsum2)
    for (int e = tid; e < BB * 64; e += 256) {
      int b = e >> 6, j = e & 63;
      float s = 0.f;
#pragma unroll 8
      for (int p = 0; p < 128; ++p)
        s += part_in[((size_t)b * 128 + p) * DD + j0 + j];
      ss[b][j] = s;
    }
    __syncthreads();
    float a[BB][2];
#pragma unroll
    for (int b = 0; b < BB; ++b) { a[b][0] = 0.f; a[b][1] = 0.f; }
    for (int j = 0; j < 64; ++j) {
      float w0 = W[(size_t)(j0 + j) * DD + tid];
      float w1 = W[(size_t)(j0 + j) * DD + tid + 256];
#pragma unroll
      for (int b = 0; b < BB; ++b) {
        float sv = ss[b][j];
        a[b][0] += sv * w0;
        a[b][1] += sv * w1;
      }
    }
    float* part = which ? partK : partQ;
#pragma unroll
    for (int b = 0; b < BB; ++b) {
      part[((size_t)jc * BB + b) * DD + tid] = a[b][0];
      part[((size_t)jc * BB + b) * DD + tid + 256] = a[b][1];
    }
    return;
  }

  // ---- wvot path: WT[c][j0..j0+8] = bf16((Wv @ Wo)^T) ----
  int b2 = bid - 24;
  int cb = b2 & 1, jg = b2 >> 1;
  int c = cb * 256 + tid;
  int j0 = jg * 8;
  for (int t = tid; t < 8 * 512; t += 256)
    wv[t >> 9][t & 511] = Wv[(size_t)(j0 + (t >> 9)) * DD + (t & 511)];
  __syncthreads();
  float acc[8] = {0, 0, 0, 0, 0, 0, 0, 0};
  for (int m = 0; m < DD; ++m) {
    float wo = Wo[(size_t)m * DD + c];
#pragma unroll
    for (int j = 0; j < 8; ++j) acc[j] += wv[j][m] * wo;
  }
  ushort4 o0, o1;
  o0.x = f2bf(acc[0]); o0.y = f2bf(acc[1]); o0.z = f2bf(acc[2]); o0.w = f2bf(acc[3]);
  o1.x = f2bf(acc[4]); o1.y = f2bf(acc[5]); o1.z = f2bf(acc[6]); o1.w = f2bf(acc[7]);
  *(ushort4*)&WT[(size_t)c * DD + j0] = o0;
  *(ushort4*)&WT[(size_t)c * DD + j0 + 4] = o1;
}

// ------- K3: reduce proj partials, mean_value, top-41, softmax, bvo -------
__global__ __launch_bounds__(512) void k_stats2(
    const float* __restrict__ partQ, const float* __restrict__ partK,
    const float* __restrict__ partO,
    const float* __restrict__ bq, const float* __restrict__ bk,
    const float* __restrict__ bo,
    int* __restrict__ idx_out, float* __restrict__ wts_out,
    float* __restrict__ bvo_out) {
  __shared__ float Sq[BB][DD];
  __shared__ float Sk[BB][DD];
  __shared__ float mvs[BB][64];
  __shared__ float mab[64];
  __shared__ int idxs[64];
  int tid = threadIdx.x;
  float bqv = bq[tid] * (float)LL, bkv = bk[tid] * (float)LL;
#pragma unroll
  for (int b = 0; b < BB; ++b) {
    float aq = 0.f, ak = 0.f;
#pragma unroll
    for (int jc = 0; jc < 8; ++jc) {
      aq += partQ[((size_t)jc * BB + b) * DD + tid];
      ak += partK[((size_t)jc * BB + b) * DD + tid];
    }
    Sq[b][tid] = aq + bqv;
    Sk[b][tid] = ak + bkv;
  }
  {
    float ao = 0.f;
#pragma unroll
    for (int jc = 0; jc < 8; ++jc) ao += partO[(size_t)jc * DD + tid];
    bvo_out[tid] = ao + bo[tid];
  }
  __syncthreads();
  {
    int b = tid >> 6, d = tid & 63;
    float s = 0.f;
#pragma unroll
    for (int h = 0; h < 8; ++h) s += Sq[b][h * 64 + d] * Sk[b][h * 64 + d];
    mvs[b][d] = s * (1.0f / ((float)LL * 8.0f));
  }
  __syncthreads();
  if (tid < 64) {
    float s = 0.f;
#pragma unroll
    for (int b = 0; b < BB; ++b) s += mvs[b][tid];
    mab[tid] = s * 0.125f;
  }
  __syncthreads();
  if (tid < 64) {
    float x = mab[tid];
    int r = 0;
    for (int d = 0; d < 64; ++d) {
      float y = mab[d];
      r += (y > x || (y == x && d < tid)) ? 1 : 0;
    }
    if (r < KSEL) { idxs[r] = tid; idx_out[r] = tid; }
  }
  __syncthreads();
  if (tid < BB) {
    int b = tid;
    float mx = -3.4e38f;
    for (int i = 0; i < KSEL; ++i) mx = fmaxf(mx, mvs[b][idxs[i]]);
    float s = 0.f;
    for (int i = 0; i < KSEL; ++i) s += expf(mvs[b][idxs[i]] - mx);
    float inv = 1.f / s;
    for (int i = 0; i < KSEL; ++i) wts_out[b * 64 + i] = expf(mvs[b][idxs[i]] - mx) * inv;
  }
}

// -------- K4: vagg = conv(v) via MFMA --------
__global__ __launch_bounds__(256) void k_conv(const float* __restrict__ v,
                                              const int* __restrict__ idx,
                                              const float* __restrict__ wts,
                                              ushort* __restrict__ vagg) {
  __shared__ ushort vwinT[128 * 136];
  __shared__ ushort Mlds[64 * 136];
  __shared__ float coefw[256];
  int lt = blockIdx.x;
  int ch0 = blockIdx.y * 128;
  int b = blockIdx.z;
  int tid = threadIdx.x;
  int l0 = lt * 64;

  coefw[tid] = 0.f;
  __syncthreads();
  if (tid < KSEL) coefw[64 + idx[tid]] = wts[b * 64 + tid];
  __syncthreads();

  {
    int c = tid & 127;
    int jh = tid >> 7;
    const float* vb = v + (size_t)b * LL * DD + ch0 + c;
#pragma unroll
    for (int it = 0; it < 8; ++it) {
      int j0 = (it * 2 + jh) * 8;
      union { unsigned int u[4]; short8 s; } pk;
#pragma unroll
      for (int p = 0; p < 4; ++p) {
        int ja = (l0 + j0 + 2 * p) & (LL - 1);
        int jb = (l0 + j0 + 2 * p + 1) & (LL - 1);
        float lo = vb[(size_t)ja * DD];
        float hi = vb[(size_t)jb * DD];
        pk.u[p] = (unsigned)f2bf(lo) | ((unsigned)f2bf(hi) << 16);
      }
      *(short8*)&vwinT[c * 136 + j0] = pk.s;
    }
  }
#pragma unroll
  for (int it = 0; it < 8; ++it) {
    int e = (it * 256 + tid) * 4;
    int r = e >> 7, j0 = e & 127;
    ushort4 m4;
    m4.x = f2bf(coefw[64 + j0 + 0 - r]);
    m4.y = f2bf(coefw[64 + j0 + 1 - r]);
    m4.z = f2bf(coefw[64 + j0 + 2 - r]);
    m4.w = f2bf(coefw[64 + j0 + 3 - r]);
    *(ushort4*)&Mlds[r * 136 + j0] = m4;
  }
  __syncthreads();

  int lane = tid & 63, w = tid >> 6;
  int r15 = lane & 15, g = lane >> 4;
  f32x4 acc[4][2] = {};
#pragma unroll
  for (int ks = 0; ks < 4; ++ks) {
    int kc = ks * 4 + g;
    short8 av[4], bvv[2];
#pragma unroll
    for (int m = 0; m < 4; ++m)
      av[m] = *(const short8*)&Mlds[(m * 16 + r15) * 136 + kc * 8];
#pragma unroll
    for (int n = 0; n < 2; ++n)
      bvv[n] = *(const short8*)&vwinT[(w * 32 + n * 16 + r15) * 136 + kc * 8];
#pragma unroll
    for (int m = 0; m < 4; ++m)
#pragma unroll
      for (int n = 0; n < 2; ++n)
        acc[m][n] = __builtin_amdgcn_mfma_f32_16x16x32_bf16(av[m], bvv[n], acc[m][n], 0, 0, 0);
  }

  ushort* vout = vagg + ((size_t)b * LL + l0) * DD + ch0;
#pragma unroll
  for (int m = 0; m < 4; ++m)
#pragma unroll
    for (int n = 0; n < 2; ++n)
#pragma unroll
      for (int r = 0; r < 4; ++r) {
        int row = m * 16 + g * 4 + r;
        int col = w * 32 + n * 16 + r15;
        vout[(size_t)row * DD + col] = f2bf(acc[m][n][r]);
      }
}

// -------- K5: out = vagg(bf16) @ Wvo(bf16, stored transposed) + bvo  (f32) --------
__global__ __launch_bounds__(256) void k_gemm(const ushort* __restrict__ A,
                                              const ushort* __restrict__ BT,
                                              const float* __restrict__ bias,
                                              float* __restrict__ C) {
  __shared__ ushort lA[128 * 64];
  __shared__ ushort lB[128 * 64];
  int bcol = blockIdx.x * 128;
  int brow = blockIdx.y * 128;
  int tid = threadIdx.x;
  int lane = tid & 63, wid = tid >> 6;
  int wr = wid >> 1, wc = wid & 1;
  int r15 = lane & 15, g = lane >> 4;
  f32x4 acc[4][4] = {};
  for (int k0 = 0; k0 < DD; k0 += 64) {
#pragma unroll
    for (int it = 0; it < 4; ++it) {
      int ch = it * 256 + tid;
      int row = ch >> 3;
      int clg = (ch & 7) ^ (row & 7);
      g2lds16(A + (size_t)(brow + row) * DD + k0 + clg * 8, &lA[ch * 8]);
      g2lds16(BT + (size_t)(bcol + row) * DD + k0 + clg * 8, &lB[ch * 8]);
    }
    asm volatile("s_waitcnt vmcnt(0)" ::: "memory");
    __syncthreads();
#pragma unroll
    for (int ks = 0; ks < 2; ++ks) {
      int kc = ks * 4 + g;
      short8 av[4], bv[4];
#pragma unroll
      for (int m = 0; m < 4; ++m) {
        int row = wr * 64 + m * 16 + r15;
        av[m] = *(const short8*)&lA[(row * 8 + (kc ^ (row & 7))) * 8];
        int col = wc * 64 + m * 16 + r15;
        bv[m] = *(const short8*)&lB[(col * 8 + (kc ^ (col & 7))) * 8];
      }
#pragma unroll
      for (int m = 0; m < 4; ++m)
#pragma unroll
        for (int n = 0; n < 4; ++n)
          acc[m][n] = __builtin_amdgcn_mfma_f32_16x16x32_bf16(av[m], bv[n], acc[m][n], 0, 0, 0);
    }
    __syncthreads();
  }
#pragma unroll
  for (int n = 0; n < 4; ++n) {
    int col = bcol + wc * 64 + n * 16 + r15;
    float bc = bias[col];
#pragma unroll
    for (int m = 0; m < 4; ++m) {
      int row = brow + wr * 64 + m * 16 + g * 4;
#pragma unroll
      for (int r = 0; r < 4; ++r)
        C[(size_t)(row + r) * DD + col] = acc[m][n][r] + bc;
    }
  }
}

extern "C" void kernel_launch(void* const* d_in, const int* in_sizes, int n_in,
                              void* d_out, int out_size, void* d_ws, size_t ws_size,
                              hipStream_t stream) {
  const float* q  = (const float*)d_in[0];
  const float* k  = (const float*)d_in[1];
  const float* v  = (const float*)d_in[2];
  const float* Wq = (const float*)d_in[3];
  const float* bq = (const float*)d_in[4];
  const float* Wk = (const float*)d_in[5];
  const float* bk = (const float*)d_in[6];
  const float* Wv = (const float*)d_in[7];
  const float* bv = (const float*)d_in[8];
  const float* Wo = (const float*)d_in[9];
  const float* bo = (const float*)d_in[10];
  float* out = (float*)d_out;

  char* ws = (char*)d_ws;
  ushort* vagg  = (ushort*)(ws + 0x0);        // 32 MB bf16 [B*L*D]
  ushort* wvot  = (ushort*)(ws + 0x2100000);  // 512 KB bf16 [D][D] transposed
  int*   idx    = (int*)(ws + 0x2388800);     // 256 B
  float* wts    = (float*)(ws + 0x2388900);   // 2 KB
  float* bvo    = (float*)(ws + 0x2389100);   // 2 KB
  // colsum partials overlay vagg region (dead until k_conv, stream-ordered):
  float* qpart  = (float*)(ws + 0x0);         // 2 MB [8][128][512]
  float* kpart  = (float*)(ws + 0x200000);    // 2 MB
  // proj partials (dead after k_stats2):
  float* partQ  = (float*)(ws + 0x2180000);   // 128 KB
  float* partK  = (float*)(ws + 0x21A0000);   // 128 KB
  float* partO  = (float*)(ws + 0x21C0000);   // 16 KB

  k_colsum<<<dim3(16, 8, 2), 512, 0, stream>>>(q, k, qpart, kpart);
  k_projw<<<dim3(152), 256, 0, stream>>>(qpart, kpart, Wq, Wk, bv, Wo, Wv,
                                         partQ, partK, partO, wvot);
  k_stats2<<<dim3(1), 512, 0, stream>>>(partQ, partK, partO, bq, bk, bo, idx, wts, bvo);
  k_conv<<<dim3(64, 4, 8), 256, 0, stream>>>(v, idx, wts, vagg);
  k_gemm<<<dim3(4, 256), 256, 0, stream>>>(vagg, wvot, bvo, out);
}